// Round 6
// baseline (427.488 us; speedup 1.0000x reference)
//
#include <hip/hip_runtime.h>
#include <hip/hip_bf16.h>

#define TT 1024
#define DM 256
#define BCN 32

typedef __attribute__((ext_vector_type(8))) short short8;
typedef __attribute__((ext_vector_type(4))) short short4v;
typedef __attribute__((ext_vector_type(4))) float f32x4;

// Barrier with LDS-only drain: ds ops ordered (lgkmcnt), but register-destined
// global loads stay in flight across it (no vmcnt(0) stall).
__device__ __forceinline__ void wg_barrier_lds() {
  asm volatile("s_waitcnt lgkmcnt(0)\n\ts_barrier" ::: "memory");
}

__device__ __forceinline__ short bf16b(float f) {
  __hip_bfloat16 h = __float2bfloat16(f);
  return *(short*)&h;
}

// ---------------------------------------------------------------------------
// Kernel 1 (fused): blocks 0..511 = QKV projection; blocks 512..1023 = mask
// int32 -> bitpack (1 bit/elem). Independent outputs, safe to fuse.
// QKV: Xs transposed once (register 4x4 transpose -> b64 writes); 12 e-tiles,
// W prefetched fp32, converted to packed bf16 b64 writes.
// Q,K stored (bc,t,d) bf16; V stored transposed (bc,e,t) bf16.
// ---------------------------------------------------------------------------
__global__ __launch_bounds__(256) __attribute__((amdgpu_waves_per_eu(2, 2)))
void qkv_kernel(const float* __restrict__ x, const float* __restrict__ w_qkv,
                const float* __restrict__ b_qkv, const int* __restrict__ mask,
                __hip_bfloat16* __restrict__ Qb, __hip_bfloat16* __restrict__ Kb,
                __hip_bfloat16* __restrict__ Vtb, unsigned* __restrict__ mbits)
{
  const int tid = threadIdx.x;

  if (blockIdx.x >= 512) {  // ---- mask bitpack blocks ----
    const int g = (blockIdx.x - 512) * 256 + tid;  // 0..131071
#pragma unroll
    for (int k = 0; k < 8; ++k) {
      const int word = g + k * 131072;             // word-owner per thread
      const int4* mp = (const int4*)mask + (size_t)word * 8;
      unsigned w = 0;
#pragma unroll
      for (int i = 0; i < 8; ++i) {
        const int4 v = mp[i];
        w |= ((unsigned)(v.x != 0) << (4 * i)) |
             ((unsigned)(v.y != 0) << (4 * i + 1)) |
             ((unsigned)(v.z != 0) << (4 * i + 2)) |
             ((unsigned)(v.w != 0) << (4 * i + 3));
      }
      mbits[word] = w;
    }
    return;
  }

  // ---- qkv blocks ----
  const int tt = blockIdx.x & 15, bc = blockIdx.x >> 4;
  const int t0 = tt * 64;

  __shared__ __attribute__((aligned(16))) __hip_bfloat16 Xs[64][264]; // [t][d]
  __shared__ __attribute__((aligned(16))) __hip_bfloat16 Ws[64][264]; // [e][d]

  const int w = tid >> 6, l = tid & 63, quad = l >> 4, lm = l & 15;
  const float* xbc = x + (size_t)bc * DM * TT;

  // transpose-stage Xs[t][d] = x[d][t0+t]: float4 rows -> 4x4 register
  // transpose -> b64 packed writes.
  {
    const int t4 = (tid & 15) * 4;
    for (int s = 0; s < 4; ++s) {
      const int d4 = (tid >> 4) * 4 + s * 64;
      f32x4 f[4];
#pragma unroll
      for (int r = 0; r < 4; ++r)
        f[r] = *(const f32x4*)(xbc + (size_t)(d4 + r) * TT + t0 + t4);
#pragma unroll
      for (int r = 0; r < 4; ++r) {
        short4v pk;
#pragma unroll
        for (int c = 0; c < 4; ++c) pk[c] = bf16b(f[c][r]);
        *(short4v*)&Xs[t4 + r][d4] = pk;
      }
    }
  }

  const float4* wv4 = (const float4*)w_qkv;  // 64 float4 per 256-col row
  float4 wr[16];
#define LOADW(ET)                                                 \
  {                                                               \
    _Pragma("unroll") for (int i = 0; i < 16; ++i)                \
        wr[i] = wv4[(size_t)(ET) * 4096 + tid + i * 256];         \
  }
  LOADW(0);

  for (int et = 0; et < 12; ++et) {
    const int e0 = et * 64;
    const bool vmode = (et >= 8);
    wg_barrier_lds();  // prev iter done reading Ws; Xs writes drained on et=0
#pragma unroll
    for (int i = 0; i < 16; ++i) {
      const int idx = tid + i * 256, row = idx >> 6, c4 = idx & 63;
      const float4 f = wr[i];
      short4v pk;
      pk[0] = bf16b(f.x); pk[1] = bf16b(f.y);
      pk[2] = bf16b(f.z); pk[3] = bf16b(f.w);
      *(short4v*)&Ws[row][c4 * 4] = pk;  // one b64 per chunk
    }
    if (et < 11) LOADW(et + 1);  // stays in flight across barrier
    wg_barrier_lds();

    f32x4 acc[4] = {};
#pragma unroll
    for (int ks = 0; ks < 8; ++ks) {
      const int k = ks * 32 + quad * 8;
      const short8 xa = *(const short8*)&Xs[w * 16 + lm][k];
#pragma unroll
      for (int nt = 0; nt < 4; ++nt) {
        const short8 wb = *(const short8*)&Ws[nt * 16 + lm][k];
        // Q/K: D[e][t] (A=W,B=X) -> 4 consecutive e per lane.
        // V:   D[t][e] (A=X,B=W) -> 4 consecutive t per lane.
        acc[nt] = vmode
            ? __builtin_amdgcn_mfma_f32_16x16x32_bf16(xa, wb, acc[nt], 0, 0, 0)
            : __builtin_amdgcn_mfma_f32_16x16x32_bf16(wb, xa, acc[nt], 0, 0, 0);
      }
    }

    if (!vmode) {
      // lane: t = t0+w*16+lm fixed; e = e0+nt*16+quad*4+r (4 consecutive)
      const int t = t0 + w * 16 + lm;
#pragma unroll
      for (int nt = 0; nt < 4; ++nt) {
        const int ebase = e0 + nt * 16 + quad * 4;  // 0..511
        short4v pk;
#pragma unroll
        for (int r = 0; r < 4; ++r) pk[r] = bf16b(acc[nt][r] + b_qkv[ebase + r]);
        __hip_bfloat16* dst = (et < 4) ? Qb : Kb;
        const int eloc = ebase & 255;
        *(short4v*)&dst[((size_t)bc * TT + t) * DM + eloc] = pk;
      }
    } else {
      // lane: e = (e0-512)+nt*16+lm fixed; t = t0+w*16+quad*4+r (consecutive)
      const int tbase = t0 + w * 16 + quad * 4;
#pragma unroll
      for (int nt = 0; nt < 4; ++nt) {
        const int e = (e0 - 512) + nt * 16 + lm;
        const float bq = b_qkv[512 + e];
        short4v pk;
#pragma unroll
        for (int r = 0; r < 4; ++r) pk[r] = bf16b(acc[nt][r] + bq);
        *(short4v*)&Vtb[((size_t)bc * DM + e) * TT + tbase] = pk;
      }
    }
  }
#undef LOADW
}

// ---------------------------------------------------------------------------
// Kernel 2: flash attention. Computes S^T (A=K,B=Q) and O^T (A=V^T,B=P) so
// all LDS/global stores are packed b64. Fixed-max softmax p=exp(s/16-8);
// l via ones-A MFMA. Distance-2 register prefetch with TWO NAMED register
// sets (compile-time indices only — runtime-indexed arrays spill to scratch).
// XCD swizzle: each XCD's 64 co-resident blocks share 4 bc (K/V fit its L2).
// Br=64 (4 waves x 16 q), Kc=32, 32 iters. grid 512 flat.
// ---------------------------------------------------------------------------
__global__ __launch_bounds__(256) __attribute__((amdgpu_waves_per_eu(2, 2)))
void attn_kernel(const __hip_bfloat16* __restrict__ Qb,
                 const __hip_bfloat16* __restrict__ Kb,
                 const __hip_bfloat16* __restrict__ Vtb,
                 const unsigned* __restrict__ Mbits,
                 __hip_bfloat16* __restrict__ Ob)
{
  const int fid = blockIdx.x;
  const int xcd = fid & 7, slot = fid >> 3;
  const int bc = xcd * 4 + (slot >> 4);
  const int qt = slot & 15;
  const int q0 = qt * 64;

  __shared__ __attribute__((aligned(16))) __hip_bfloat16 Ks[32][264];
  __shared__ __attribute__((aligned(16))) __hip_bfloat16 Vs[256][40];
  __shared__ __attribute__((aligned(16))) __hip_bfloat16 Ps[64][40];
  __shared__ unsigned Msb[64];  // 1 bit per key column, word per q row

  const int tid = threadIdx.x, w = tid >> 6, l = tid & 63;
  const int quad = l >> 4, lm = l & 15;

  // Q fragments from global (B-operand: lane n=lm -> q row w*16+lm)
  const __hip_bfloat16* Qg =
      Qb + ((size_t)bc * TT + q0 + w * 16 + lm) * DM + quad * 8;
  short8 qf[8];
#pragma unroll
  for (int ks = 0; ks < 8; ++ks) qf[ks] = *(const short8*)(Qg + ks * 32);

  // staging coordinates
  const int k_r = tid >> 5, k_c = (tid & 31) * 8;  // K: 32 x 256
  const int v_r = tid >> 2, v_c = (tid & 3) * 8;   // V^T: 256 x 32
  const __hip_bfloat16* KgB = Kb + ((size_t)bc * TT + k_r) * DM + k_c;
  const __hip_bfloat16* VgB = Vtb + ((size_t)bc * DM + v_r) * TT + v_c;
  const unsigned* MgB = Mbits + ((size_t)bc * TT + q0 + (tid & 63)) * 32;

  uint4 kr0[4], vr0[4], kr1[4], vr1[4];
  unsigned mr0 = 0, mr1 = 0;
#define LOADJ(J, KR, VR, MR)                                              \
  {                                                                       \
    _Pragma("unroll") for (int i = 0; i < 4; ++i)                         \
        KR[i] = *(const uint4*)(KgB + ((size_t)(J) * 32 + i * 8) * DM);   \
    _Pragma("unroll") for (int i = 0; i < 4; ++i)                         \
        VR[i] = *(const uint4*)(VgB + (size_t)i * 64 * TT + (J) * 32);    \
    if (tid < 64) MR = MgB[(J)];                                          \
  }

  short8 ones;
#pragma unroll
  for (int i = 0; i < 8; ++i) ones[i] = (short)0x3F80;  // bf16 1.0

  f32x4 Oa[16] = {};  // O^T fragments: lane col q=w*16+lm, rows e
  f32x4 Ol = {};      // per-q l (every reg row equal)

  // stage tile (KR,VR,MR) -> LDS; then compute on it (no j dependence).
#define STAGE(KR, VR, MR)                                                 \
  {                                                                       \
    _Pragma("unroll") for (int i = 0; i < 4; ++i)                         \
        *(uint4*)&Ks[k_r + i * 8][k_c] = KR[i];                           \
    _Pragma("unroll") for (int i = 0; i < 4; ++i)                         \
        *(uint4*)&Vs[v_r + i * 64][v_c] = VR[i];                          \
    if (tid < 64) Msb[tid] = MR;                                          \
  }

#define COMPUTE()                                                           \
  {                                                                         \
    f32x4 Sa[2] = {};                                                       \
    _Pragma("unroll") for (int ks = 0; ks < 8; ++ks) {                      \
      const short8 a0 = *(const short8*)&Ks[lm][ks * 32 + quad * 8];        \
      const short8 a1 = *(const short8*)&Ks[16 + lm][ks * 32 + quad * 8];   \
      Sa[0] =                                                               \
          __builtin_amdgcn_mfma_f32_16x16x32_bf16(a0, qf[ks], Sa[0], 0, 0, 0); \
      Sa[1] =                                                               \
          __builtin_amdgcn_mfma_f32_16x16x32_bf16(a1, qf[ks], Sa[1], 0, 0, 0); \
    }                                                                       \
    const unsigned mw = Msb[w * 16 + lm];                                   \
    _Pragma("unroll") for (int nt = 0; nt < 2; ++nt) {                      \
      short4v pk;                                                           \
      _Pragma("unroll") for (int r = 0; r < 4; ++r) {                       \
        const int jj = nt * 16 + quad * 4 + r;                              \
        const float p = ((mw >> jj) & 1u)                                   \
                            ? 0.f                                           \
                            : __expf(fmaf(Sa[nt][r], 0.0625f, -8.0f));      \
        pk[r] = bf16b(p);                                                   \
      }                                                                     \
      *(short4v*)&Ps[w * 16 + lm][nt * 16 + quad * 4] = pk;                 \
    }                                                                       \
    const short8 pf = *(const short8*)&Ps[w * 16 + lm][quad * 8];           \
    _Pragma("unroll") for (int ct = 0; ct < 16; ++ct) {                     \
      const short8 a = *(const short8*)&Vs[ct * 16 + lm][quad * 8];         \
      Oa[ct] = __builtin_amdgcn_mfma_f32_16x16x32_bf16(a, pf, Oa[ct], 0, 0, 0); \
    }                                                                       \
    Ol = __builtin_amdgcn_mfma_f32_16x16x32_bf16(ones, pf, Ol, 0, 0, 0);    \
  }

  LOADJ(0, kr0, vr0, mr0);
  LOADJ(1, kr1, vr1, mr1);
#pragma unroll 1
  for (int j2 = 0; j2 < 32; j2 += 2) {
    // ---- even tile: register set 0 ----
    wg_barrier_lds();            // consumers of previous tile done (lgkm only)
    STAGE(kr0, vr0, mr0);        // vmcnt for set-0 prefetch lands here
    if (j2 + 2 < 32) LOADJ(j2 + 2, kr0, vr0, mr0);
    wg_barrier_lds();            // tile visible
    COMPUTE();
    // ---- odd tile: register set 1 ----
    wg_barrier_lds();
    STAGE(kr1, vr1, mr1);
    if (j2 + 3 < 32) LOADJ(j2 + 3, kr1, vr1, mr1);
    wg_barrier_lds();
    COMPUTE();
  }
#undef LOADJ
#undef STAGE
#undef COMPUTE

  // normalize + write O (bf16, (t,e)-major): lane q = w*16+lm, 4 consecutive e
  const float inv = 1.0f / Ol[0];
  __hip_bfloat16* Og = Ob + ((size_t)bc * TT + q0 + w * 16 + lm) * DM;
#pragma unroll
  for (int ct = 0; ct < 16; ++ct) {
    short4v pk;
#pragma unroll
    for (int r = 0; r < 4; ++r) pk[r] = bf16b(Oa[ct][r] * inv);
    *(short4v*)&Og[ct * 16 + quad * 4] = pk;  // one b64 store
  }
}

// ---------------------------------------------------------------------------
// Kernel 3: output projection. y[t][f] = sum_e O[t][e] w_out[f][e] + b_out[f]
// A=W (rows f), B=O (cols t) -> lane holds 4 consecutive f -> float4 stores.
// grid (4 ftiles, 16 ttiles, 32 bc), 256 threads.
// ---------------------------------------------------------------------------
__global__ __launch_bounds__(256) __attribute__((amdgpu_waves_per_eu(2, 2)))
void proj_kernel(const __hip_bfloat16* __restrict__ Ob,
                 const float* __restrict__ w_out,
                 const float* __restrict__ b_out, float* __restrict__ out)
{
  const int ft = blockIdx.x, tt = blockIdx.y, bc = blockIdx.z;
  const int f0 = ft * 64, t0 = tt * 64;

  __shared__ __attribute__((aligned(16))) __hip_bfloat16 As[64][264];
  __shared__ __attribute__((aligned(16))) __hip_bfloat16 Bs[64][264];

  const int tid = threadIdx.x;
  const uint4* Og4 = (const uint4*)(Ob + ((size_t)bc * TT + t0) * DM);
  uint4 ar[8];
  float4 br[16];
#pragma unroll
  for (int i = 0; i < 8; ++i) ar[i] = Og4[tid + i * 256];
  {
    const float4* wv = (const float4*)(w_out + (size_t)f0 * DM);
#pragma unroll
    for (int i = 0; i < 16; ++i) br[i] = wv[tid + i * 256];
  }
#pragma unroll
  for (int i = 0; i < 8; ++i) {
    const int chunk = tid + i * 256, row = chunk >> 5, c8 = chunk & 31;
    *(uint4*)&As[row][c8 * 8] = ar[i];
  }
#pragma unroll
  for (int i = 0; i < 16; ++i) {
    const int idx = tid + i * 256, row = idx >> 6, c4 = idx & 63;
    const float4 f = br[i];
    short4v pk;
    pk[0] = bf16b(f.x); pk[1] = bf16b(f.y);
    pk[2] = bf16b(f.z); pk[3] = bf16b(f.w);
    *(short4v*)&Bs[row][c4 * 4] = pk;
  }
  __syncthreads();

  const int w = tid >> 6, l = tid & 63, quad = l >> 4, lm = l & 15;
  f32x4 acc[4] = {};
#pragma unroll
  for (int ks = 0; ks < 8; ++ks) {
    const int k = ks * 32 + quad * 8;
    const short8 ob = *(const short8*)&As[w * 16 + lm][k];   // B: cols t
#pragma unroll
    for (int nt = 0; nt < 4; ++nt) {
      const short8 wa = *(const short8*)&Bs[nt * 16 + lm][k];  // A: rows f
      acc[nt] = __builtin_amdgcn_mfma_f32_16x16x32_bf16(wa, ob, acc[nt], 0, 0, 0);
    }
  }
  // lane: t = t0+w*16+lm fixed; f = f0+nt*16+quad*4+r (4 consecutive)
  const int t = t0 + w * 16 + lm;
#pragma unroll
  for (int nt = 0; nt < 4; ++nt) {
    const int fb = f0 + nt * 16 + quad * 4;
    float4 o;
    o.x = acc[nt][0] + b_out[fb + 0];
    o.y = acc[nt][1] + b_out[fb + 1];
    o.z = acc[nt][2] + b_out[fb + 2];
    o.w = acc[nt][3] + b_out[fb + 3];
    *(float4*)&out[((size_t)bc * TT + t) * DM + fb] = o;
  }
}

// ---------------------------------------------------------------------------
extern "C" void kernel_launch(void* const* d_in, const int* in_sizes, int n_in,
                              void* d_out, int out_size, void* d_ws, size_t ws_size,
                              hipStream_t stream) {
  const float* x = (const float*)d_in[0];
  const int* mask = (const int*)d_in[1];  // bool -> int32 per harness contract
  const float* w_qkv = (const float*)d_in[2];
  const float* b_qkv = (const float*)d_in[3];
  const float* w_out = (const float*)d_in[4];
  const float* b_out = (const float*)d_in[5];
  float* out = (float*)d_out;

  const size_t N = (size_t)BCN * TT * DM;  // 8,388,608 elems
  __hip_bfloat16* Qb  = (__hip_bfloat16*)d_ws;   // 16.8 MB (reused as O)
  __hip_bfloat16* Kb  = Qb + N;                  // 16.8 MB
  __hip_bfloat16* Vtb = Kb + N;                  // 16.8 MB, [bc][e][t]
  unsigned* Mbits     = (unsigned*)(Vtb + N);    // 4 MB bitmask

  qkv_kernel<<<dim3(1024), dim3(256), 0, stream>>>(x, w_qkv, b_qkv, mask,
                                                   Qb, Kb, Vtb, Mbits);
  attn_kernel<<<dim3(512), dim3(256), 0, stream>>>(Qb, Kb, Vtb, Mbits, Qb);
  proj_kernel<<<dim3(4, 16, BCN), dim3(256), 0, stream>>>(Qb, w_out, b_out, out);
}

// Round 7
// 361.462 us; speedup vs baseline: 1.1827x; 1.1827x over previous
//
#include <hip/hip_runtime.h>
#include <hip/hip_bf16.h>

#define TT 1024
#define DM 256
#define BCN 32

typedef __attribute__((ext_vector_type(8))) short short8;
typedef __attribute__((ext_vector_type(4))) short short4v;
typedef __attribute__((ext_vector_type(4))) float f32x4;

__device__ __forceinline__ void wg_barrier_lds() {
  asm volatile("s_waitcnt lgkmcnt(0)\n\ts_barrier" ::: "memory");
}

__device__ __forceinline__ short bf16b(float f) {
  __hip_bfloat16 h = __float2bfloat16(f);
  return *(short*)&h;
}

// Direct global->LDS DMA (no VGPR round trip, tracked by vmcnt).
// LDS dest must be wave-uniform base; HW adds lane*size. gptr is per-lane.
__device__ __forceinline__ void dma16(void* l, const void* g) {
  __builtin_amdgcn_global_load_lds(
      (const __attribute__((address_space(1))) void*)g,
      (__attribute__((address_space(3))) void*)l, 16, 0, 0);
}
__device__ __forceinline__ void dma4(void* l, const void* g) {
  __builtin_amdgcn_global_load_lds(
      (const __attribute__((address_space(1))) void*)g,
      (__attribute__((address_space(3))) void*)l, 4, 0, 0);
}

// ---------------------------------------------------------------------------
// Kernel 1 (fused): blocks 0..511 = QKV projection; 512..1023 = mask bitpack.
// Q stored (bc,t,d) bf16 unswizzled.
// K stored (bc,t,d_swz): 16B chunk ch of row t stored at ch^(t&7)  -> attn's
//   linear-LDS S-phase reads are bank-class balanced.
// V stored tiled: [bc][kb(32)][e(256)][t32(32)] -> each attn tile is one
//   contiguous 16 KB block for DMA.
// Mask bits: [bc][j(32)][q(1024)] one word per (q, 32-k block).
// ---------------------------------------------------------------------------
__global__ __launch_bounds__(256, 2) void qkv_kernel(
    const float* __restrict__ x, const float* __restrict__ w_qkv,
    const float* __restrict__ b_qkv, const int* __restrict__ mask,
    __hip_bfloat16* __restrict__ Qb, __hip_bfloat16* __restrict__ Kb,
    __hip_bfloat16* __restrict__ Vtb, unsigned* __restrict__ mbits)
{
  const int tid = threadIdx.x;

  if (blockIdx.x >= 512) {  // ---- mask bitpack ----
    const int g = (blockIdx.x - 512) * 256 + tid;  // 0..131071
#pragma unroll
    for (int k = 0; k < 8; ++k) {
      const int word = g + k * 131072;  // [bc][j][q]: q fastest -> coalesced
      const int bc = word >> 15, j = (word >> 10) & 31, q = word & 1023;
      const int4* mp =
          (const int4*)(mask + ((size_t)(bc * 1024 + q) * 1024 + j * 32));
      unsigned w = 0;
#pragma unroll
      for (int i = 0; i < 8; ++i) {
        const int4 v = mp[i];
        w |= ((unsigned)(v.x != 0) << (4 * i)) |
             ((unsigned)(v.y != 0) << (4 * i + 1)) |
             ((unsigned)(v.z != 0) << (4 * i + 2)) |
             ((unsigned)(v.w != 0) << (4 * i + 3));
      }
      mbits[word] = w;
    }
    return;
  }

  // ---- qkv ----
  const int tt = blockIdx.x & 15, bc = blockIdx.x >> 4;
  const int t0 = tt * 64;

  __shared__ __attribute__((aligned(16))) __hip_bfloat16 Xs[64][264]; // [t][d]
  __shared__ __attribute__((aligned(16))) __hip_bfloat16 Ws[64][264]; // [e][d]

  const int w = tid >> 6, l = tid & 63, quad = l >> 4, lm = l & 15;
  const float* xbc = x + (size_t)bc * DM * TT;

  // transpose-stage Xs[t][d] = x[d][t0+t]: 4x4 register transpose, b64 writes
  {
    const int t4 = (tid & 15) * 4;
    for (int s = 0; s < 4; ++s) {
      const int d4 = (tid >> 4) * 4 + s * 64;
      f32x4 f[4];
#pragma unroll
      for (int r = 0; r < 4; ++r)
        f[r] = *(const f32x4*)(xbc + (size_t)(d4 + r) * TT + t0 + t4);
#pragma unroll
      for (int r = 0; r < 4; ++r) {
        short4v pk;
#pragma unroll
        for (int c = 0; c < 4; ++c) pk[c] = bf16b(f[c][r]);
        *(short4v*)&Xs[t4 + r][d4] = pk;
      }
    }
  }

  const float4* wv4 = (const float4*)w_qkv;  // 64 float4 per 256-col row

  for (int et = 0; et < 12; ++et) {
    const int e0 = et * 64;
    const bool vmode = (et >= 8);
    wg_barrier_lds();  // prev iter done reading Ws (covers Xs at et=0)
    // inline load+convert W tile (no cross-barrier register residency)
#pragma unroll
    for (int i = 0; i < 16; ++i) {
      const int idx = tid + i * 256, row = idx >> 6, c4 = idx & 63;
      const float4 f = wv4[(size_t)et * 4096 + idx];
      short4v pk;
      pk[0] = bf16b(f.x); pk[1] = bf16b(f.y);
      pk[2] = bf16b(f.z); pk[3] = bf16b(f.w);
      *(short4v*)&Ws[row][c4 * 4] = pk;
    }
    wg_barrier_lds();

    f32x4 acc[4] = {};
#pragma unroll
    for (int ks = 0; ks < 8; ++ks) {
      const int k = ks * 32 + quad * 8;
      const short8 xa = *(const short8*)&Xs[w * 16 + lm][k];
#pragma unroll
      for (int nt = 0; nt < 4; ++nt) {
        const short8 wb = *(const short8*)&Ws[nt * 16 + lm][k];
        // Q/K: D[e][t] (A=W,B=X); V: D[t][e] (A=X,B=W)
        acc[nt] = vmode
            ? __builtin_amdgcn_mfma_f32_16x16x32_bf16(xa, wb, acc[nt], 0, 0, 0)
            : __builtin_amdgcn_mfma_f32_16x16x32_bf16(wb, xa, acc[nt], 0, 0, 0);
      }
    }

    if (et < 4) {
      // Q: lane t fixed, e = e0+nt*16+quad*4+r consecutive (unswizzled)
      const int t = t0 + w * 16 + lm;
#pragma unroll
      for (int nt = 0; nt < 4; ++nt) {
        const int ebase = e0 + nt * 16 + quad * 4;  // 0..255
        short4v pk;
#pragma unroll
        for (int r = 0; r < 4; ++r) pk[r] = bf16b(acc[nt][r] + b_qkv[ebase + r]);
        *(short4v*)&Qb[((size_t)bc * TT + t) * DM + ebase] = pk;
      }
    } else if (!vmode) {
      // K: swizzled chunk ch -> ch^(t&7)
      const int t = t0 + w * 16 + lm;
#pragma unroll
      for (int nt = 0; nt < 4; ++nt) {
        const int eg = e0 + nt * 16 + quad * 4;   // 256..511
        const int eK = eg - 256;                  // 0..255
        short4v pk;
#pragma unroll
        for (int r = 0; r < 4; ++r) pk[r] = bf16b(acc[nt][r] + b_qkv[eg + r]);
        const int ch = eK >> 3;
        const int off = (((ch ^ (t & 7)) << 3) | (eK & 7));
        *(short4v*)&Kb[((size_t)bc * TT + t) * DM + off] = pk;
      }
    } else {
      // V tiled: [bc][kb][e][t32], lane e fixed, t consecutive
      const int tb = w * 16 + quad * 4;           // 0..60, mult of 4
      const int kb = tt * 2 + (tb >> 5), tloc = tb & 31;
#pragma unroll
      for (int nt = 0; nt < 4; ++nt) {
        const int e = (e0 - 512) + nt * 16 + lm;
        const float bq = b_qkv[512 + e];
        short4v pk;
#pragma unroll
        for (int r = 0; r < 4; ++r) pk[r] = bf16b(acc[nt][r] + bq);
        *(short4v*)&Vtb[(((size_t)bc * 32 + kb) * 256 + e) * 32 + tloc] = pk;
      }
    }
  }
}

// ---------------------------------------------------------------------------
// Kernel 2: flash attention, global_load_lds double-buffered K-loop.
// Per iter: s_waitcnt vmcnt(9) (next tile stays in flight) -> barrier ->
// compute -> lgkm barrier -> DMA tile j+2 into freed buffer. No register
// staging => nothing to spill. S^T (A=K,B=Q), O^T (A=V,B=P), fixed-max
// softmax p=exp(s/16-8), l via ones MFMA. XCD swizzle keeps 4 bc per XCD L2.
// ---------------------------------------------------------------------------
__global__ __launch_bounds__(256, 2) void attn_kernel(
    const __hip_bfloat16* __restrict__ Qb, const __hip_bfloat16* __restrict__ Kb,
    const __hip_bfloat16* __restrict__ Vtb, const unsigned* __restrict__ Mbits,
    __hip_bfloat16* __restrict__ Ob)
{
  const int fid = blockIdx.x;
  const int xcd = fid & 7, slot = fid >> 3;
  const int bc = xcd * 4 + (slot >> 4);
  const int qt = slot & 15;
  const int q0 = qt * 64;

  __shared__ __attribute__((aligned(16))) __hip_bfloat16 Ks[2][32 * 256];
  __shared__ __attribute__((aligned(16))) __hip_bfloat16 Vs[2][256 * 32];
  __shared__ __attribute__((aligned(16))) __hip_bfloat16 Ps[64][40];
  __shared__ unsigned Msb[2][64];

  const int tid = threadIdx.x, w = tid >> 6, l = tid & 63;
  const int quad = l >> 4, lm = l & 15, lm7 = lm & 7;

  // Q fragments direct from global (unswizzled)
  const __hip_bfloat16* Qg =
      Qb + ((size_t)bc * TT + q0 + w * 16 + lm) * DM + quad * 8;
  short8 qf[8];
#pragma unroll
  for (int ks = 0; ks < 8; ++ks) qf[ks] = *(const short8*)(Qg + ks * 32);

  const char* KgT = (const char*)(Kb + (size_t)bc * TT * DM);   // +j*16384
  const char* VgT = (const char*)(Vtb + (size_t)bc * TT * DM);  // +j*16384
  const unsigned* MgT = Mbits + ((size_t)bc * 32) * 1024 + q0;  // +j*1024

  short8 ones;
#pragma unroll
  for (int i = 0; i < 8; ++i) ones[i] = (short)0x3F80;  // bf16 1.0

  f32x4 Oa[16] = {};
  f32x4 Ol = {};

  auto issue = [&](int j, int buf) {
    const char* kg = KgT + (size_t)j * 16384 + w * 4096 + l * 16;
    const char* vg = VgT + (size_t)j * 16384 + w * 4096 + l * 16;
    char* kl = (char*)&Ks[buf][0] + w * 4096;
    char* vl = (char*)&Vs[buf][0] + w * 4096;
#pragma unroll
    for (int i = 0; i < 4; ++i) dma16(kl + i * 1024, kg + i * 1024);
#pragma unroll
    for (int i = 0; i < 4; ++i) dma16(vl + i * 1024, vg + i * 1024);
    // all waves issue the (identical) mask DMA so vmcnt is uniform (9/tile)
    dma4(&Msb[buf][0], MgT + (size_t)j * 1024 + l);
  };

  auto compute = [&](int buf) {
    const __hip_bfloat16* KT = &Ks[buf][0];
    const __hip_bfloat16* VT = &Vs[buf][0];
    f32x4 Sa0 = {}, Sa1 = {};
#pragma unroll
    for (int ks = 0; ks < 8; ++ks) {
      const int c = ((ks * 4 + quad) ^ lm7) << 3;  // de-swizzle
      const short8 a0 = *(const short8*)&KT[lm * 256 + c];
      const short8 a1 = *(const short8*)&KT[(lm + 16) * 256 + c];
      Sa0 = __builtin_amdgcn_mfma_f32_16x16x32_bf16(a0, qf[ks], Sa0, 0, 0, 0);
      Sa1 = __builtin_amdgcn_mfma_f32_16x16x32_bf16(a1, qf[ks], Sa1, 0, 0, 0);
    }
    const unsigned mw = Msb[buf][w * 16 + lm];
#pragma unroll
    for (int nt = 0; nt < 2; ++nt) {
      const f32x4 Sa = nt ? Sa1 : Sa0;
      short4v pk;
#pragma unroll
      for (int r = 0; r < 4; ++r) {
        const int jj = nt * 16 + quad * 4 + r;
        const float p = ((mw >> jj) & 1u)
                            ? 0.f
                            : __expf(fmaf(Sa[r], 0.0625f, -8.0f));
        pk[r] = bf16b(p);
      }
      *(short4v*)&Ps[w * 16 + lm][nt * 16 + quad * 4] = pk;
    }
    const short8 pf = *(const short8*)&Ps[w * 16 + lm][quad * 8];
#pragma unroll
    for (int ct = 0; ct < 16; ++ct) {
      const short8 a = *(const short8*)&VT[(ct * 16 + lm) * 32 + quad * 8];
      Oa[ct] = __builtin_amdgcn_mfma_f32_16x16x32_bf16(a, pf, Oa[ct], 0, 0, 0);
    }
    Ol = __builtin_amdgcn_mfma_f32_16x16x32_bf16(ones, pf, Ol, 0, 0, 0);
  };

  issue(0, 0);
  issue(1, 1);
#pragma unroll 1
  for (int j = 0; j < 32; ++j) {
    const int buf = j & 1;
    if (j < 31)
      asm volatile("s_waitcnt vmcnt(9)" ::: "memory");  // tile j done; j+1 in flight
    else
      asm volatile("s_waitcnt vmcnt(0)" ::: "memory");
    asm volatile("s_barrier" ::: "memory");
    compute(buf);
    wg_barrier_lds();  // all waves done reading buf (lgkm only)
    if (j < 30) issue(j + 2, buf);
  }

  // normalize + write O (bf16, (t,e)-major): lane q fixed, 4 consecutive e
  const float inv = 1.0f / Ol[0];
  __hip_bfloat16* Og = Ob + ((size_t)bc * TT + q0 + w * 16 + lm) * DM;
#pragma unroll
  for (int ct = 0; ct < 16; ++ct) {
    short4v pk;
#pragma unroll
    for (int r = 0; r < 4; ++r) pk[r] = bf16b(Oa[ct][r] * inv);
    *(short4v*)&Og[ct * 16 + quad * 4] = pk;
  }
}

// ---------------------------------------------------------------------------
// Kernel 3: output projection. A=W (rows f), B=O (cols t) -> float4 stores.
// ---------------------------------------------------------------------------
__global__ __launch_bounds__(256, 2) void proj_kernel(
    const __hip_bfloat16* __restrict__ Ob, const float* __restrict__ w_out,
    const float* __restrict__ b_out, float* __restrict__ out)
{
  const int ft = blockIdx.x, tt = blockIdx.y, bc = blockIdx.z;
  const int f0 = ft * 64, t0 = tt * 64;

  __shared__ __attribute__((aligned(16))) __hip_bfloat16 As[64][264];
  __shared__ __attribute__((aligned(16))) __hip_bfloat16 Bs[64][264];

  const int tid = threadIdx.x;
  const uint4* Og4 = (const uint4*)(Ob + ((size_t)bc * TT + t0) * DM);
#pragma unroll
  for (int i = 0; i < 8; ++i) {
    const int chunk = tid + i * 256, row = chunk >> 5, c8 = chunk & 31;
    *(uint4*)&As[row][c8 * 8] = Og4[chunk];
  }
  {
    const float4* wv = (const float4*)(w_out + (size_t)f0 * DM);
#pragma unroll
    for (int i = 0; i < 16; ++i) {
      const int idx = tid + i * 256, row = idx >> 6, c4 = idx & 63;
      const float4 f = wv[idx];
      short4v pk;
      pk[0] = bf16b(f.x); pk[1] = bf16b(f.y);
      pk[2] = bf16b(f.z); pk[3] = bf16b(f.w);
      *(short4v*)&Bs[row][c4 * 4] = pk;
    }
  }
  __syncthreads();

  const int w = tid >> 6, l = tid & 63, quad = l >> 4, lm = l & 15;
  f32x4 acc[4] = {};
#pragma unroll
  for (int ks = 0; ks < 8; ++ks) {
    const int k = ks * 32 + quad * 8;
    const short8 ob = *(const short8*)&As[w * 16 + lm][k];
#pragma unroll
    for (int nt = 0; nt < 4; ++nt) {
      const short8 wa = *(const short8*)&Bs[nt * 16 + lm][k];
      acc[nt] = __builtin_amdgcn_mfma_f32_16x16x32_bf16(wa, ob, acc[nt], 0, 0, 0);
    }
  }
  const int t = t0 + w * 16 + lm;
#pragma unroll
  for (int nt = 0; nt < 4; ++nt) {
    const int fb = f0 + nt * 16 + quad * 4;
    float4 o;
    o.x = acc[nt][0] + b_out[fb + 0];
    o.y = acc[nt][1] + b_out[fb + 1];
    o.z = acc[nt][2] + b_out[fb + 2];
    o.w = acc[nt][3] + b_out[fb + 3];
    *(float4*)&out[((size_t)bc * TT + t) * DM + fb] = o;
  }
}

// ---------------------------------------------------------------------------
extern "C" void kernel_launch(void* const* d_in, const int* in_sizes, int n_in,
                              void* d_out, int out_size, void* d_ws, size_t ws_size,
                              hipStream_t stream) {
  const float* x = (const float*)d_in[0];
  const int* mask = (const int*)d_in[1];
  const float* w_qkv = (const float*)d_in[2];
  const float* b_qkv = (const float*)d_in[3];
  const float* w_out = (const float*)d_in[4];
  const float* b_out = (const float*)d_in[5];
  float* out = (float*)d_out;

  const size_t N = (size_t)BCN * TT * DM;
  __hip_bfloat16* Qb  = (__hip_bfloat16*)d_ws;   // 16.8 MB (reused as O)
  __hip_bfloat16* Kb  = Qb + N;                  // 16.8 MB, swizzled rows
  __hip_bfloat16* Vtb = Kb + N;                  // 16.8 MB, 16 KB tiles
  unsigned* Mbits     = (unsigned*)(Vtb + N);    // 4 MB, [bc][j][q]

  qkv_kernel<<<dim3(1024), dim3(256), 0, stream>>>(x, w_qkv, b_qkv, mask,
                                                   Qb, Kb, Vtb, Mbits);
  attn_kernel<<<dim3(512), dim3(256), 0, stream>>>(Qb, Kb, Vtb, Mbits, Qb);
  proj_kernel<<<dim3(4, 16, BCN), dim3(256), 0, stream>>>(Qb, w_out, b_out, out);
}